// Round 1
// baseline (426.685 us; speedup 1.0000x reference)
//
#include <hip/hip_runtime.h>
#include <cstdint>
#include <cstddef>

#define NN 8192
#define FIN 256
#define HH 64
#define SPLIT 16
#define KLEN (NN / SPLIT)   // 512

typedef float vf4 __attribute__((ext_vector_type(4)));
typedef short vbf8 __attribute__((ext_vector_type(8)));

__device__ inline unsigned pk_trunc(float lo, float hi) {
  return __builtin_amdgcn_perm(__float_as_uint(hi), __float_as_uint(lo), 0x07060302u);
}
__device__ inline unsigned short bf_rne(float x) {
  unsigned u = __float_as_uint(x);
  return (unsigned short)((u + 0x7FFFu + ((u >> 16) & 1u)) >> 16);
}
__device__ inline float bf_to_f(unsigned short s) {
  return __uint_as_float(((unsigned)s) << 16);
}

union FragU { unsigned u[4]; unsigned short s[8]; vbf8 v; };

__device__ inline vbf8 frag_trunc(vf4 a, vf4 b) {
  FragU t;
  t.u[0] = pk_trunc(a[0], a[1]);
  t.u[1] = pk_trunc(a[2], a[3]);
  t.u[2] = pk_trunc(b[0], b[1]);
  t.u[3] = pk_trunc(b[2], b[3]);
  return t.v;
}
__device__ inline vbf8 frag_rne(vf4 a, vf4 b) {
  FragU t;
  t.s[0] = bf_rne(a[0]); t.s[1] = bf_rne(a[1]); t.s[2] = bf_rne(a[2]); t.s[3] = bf_rne(a[3]);
  t.s[4] = bf_rne(b[0]); t.s[5] = bf_rne(b[1]); t.s[6] = bf_rne(b[2]); t.s[7] = bf_rne(b[3]);
  return t.v;
}

__device__ inline void gl_lds16(const void* g, void* l) {
  __builtin_amdgcn_global_load_lds(
      (const __attribute__((address_space(1))) void*)g,
      (__attribute__((address_space(3))) void*)l, 16, 0, 0);
}

// ---------------- k1: fts = seq @ fc_w^T (both seqs), write Bt[n][k] bf16 -----
__global__ __launch_bounds__(256) void k1_fts(
    const float* __restrict__ seq1, const float* __restrict__ seq2,
    const float* __restrict__ fcw, unsigned short* __restrict__ Bt,
    float* __restrict__ csum) {
  const int bx = blockIdx.x;           // 256 blocks
  const int s = bx & 1, mb = bx >> 1;
  const int wave = threadIdx.x >> 6, lane = threadIdx.x & 63;
  const int r = lane & 15, q = lane >> 4;
  const int m0 = mb * 64 + wave * 16;
  if (bx == 0 && threadIdx.x < 64) csum[threadIdx.x] = 0.f;
  const float* seq = s ? seq2 : seq1;
  const float* ap = seq + (size_t)(m0 + r) * FIN + q * 8;
  const float* bp = fcw + (size_t)r * FIN + q * 8;
  vf4 acc[4] = {};
#pragma unroll
  for (int kk = 0; kk < FIN; kk += 32) {
    vf4 a0 = *(const vf4*)ap;
    vf4 a1 = *(const vf4*)(ap + 4);
    vbf8 af = frag_rne(a0, a1);
#pragma unroll
    for (int f = 0; f < 4; ++f) {
      vf4 b0 = *(const vf4*)(bp + (size_t)f * 16 * FIN);
      vf4 b1 = *(const vf4*)(bp + (size_t)f * 16 * FIN + 4);
      vbf8 bfr = frag_rne(b0, b1);
      acc[f] = __builtin_amdgcn_mfma_f32_16x16x32_bf16(af, bfr, acc[f], 0, 0, 0);
    }
    ap += 32; bp += 32;
  }
#pragma unroll
  for (int f = 0; f < 4; ++f) {
    short4 v;
    v.x = (short)bf_rne(acc[f][0]);
    v.y = (short)bf_rne(acc[f][1]);
    v.z = (short)bf_rne(acc[f][2]);
    v.w = (short)bf_rne(acc[f][3]);
    unsigned short* dst = Bt + (size_t)(64 * s + 16 * f + r) * NN + m0 + q * 4;
    *(short4*)dst = v;
  }
}

// ---------------- k2: Cpart[slice][n][m] = (adj[:,ks] @ B[ks,:])^T -----------
// Block: 512 thr = 8 waves, each wave 32 m-rows x 128 n. M_B=256.
// B slice staged to LDS in fragment order via global_load_lds w=16; K-chunk=128
// (2x32 KB double buffer). Counted-vmcnt barriers (T4): vmcnt(4) guarantees my
// stage(ch) loads retired (FIFO: older than the 4 newest) while the 4-load adj
// prefetch survives the barrier -> no per-chunk pipeline drain/restart bubble.
// Explicit one-kk-ahead adj register prefetch keeps 4 loads in flight always.
__global__ __launch_bounds__(512, 4) void k2_agg(
    const float* __restrict__ adj, const unsigned short* __restrict__ Bt,
    unsigned short* __restrict__ Cpart) {
  constexpr int CHUNKS = KLEN / 128;       // 4
  __shared__ unsigned short lds[2][16384]; // 2 x 32 KB
  const int bx = blockIdx.x;
  const int slice = bx & (SPLIT - 1), mb = bx / SPLIT;
  const int wave = threadIdx.x >> 6, lane = threadIdx.x & 63;
  const int r = lane & 15, q = lane >> 4;
  const int m0 = mb * 256 + wave * 32;
  const int k0 = slice * KLEN;

  // granule g (16 B) at lds offset g*16 holds Bt[f*16+r'][k0+ch*128+kk*32+q'*8]
  // with g = kk*512 + f*64 + q'*16 + r'; compute-side ds_read for frag (kk,f)
  // at granules (kk*512+f*64) + lane is then lane-contiguous, conflict-free.
  auto stage = [&](int ch, int b) {
#pragma unroll
    for (int j = 0; j < 4; ++j) {
      const int g = j * 512 + wave * 64 + lane;
      const int r_ = g & 15, q_ = (g >> 4) & 3, f_ = (g >> 6) & 7, kk_ = g >> 9;
      const unsigned short* src =
          Bt + (size_t)(f_ * 16 + r_) * NN + k0 + ch * 128 + kk_ * 32 + q_ * 8;
      gl_lds16(src, &lds[b][(size_t)(j * 512 + wave * 64) * 8]);
    }
  };

  vf4 acc0[8] = {}, acc1[8] = {};
  const float* a0p = adj + (size_t)(m0 + r) * NN + k0 + q * 8;
  const float* a1p = a0p + (size_t)16 * NN;

  stage(0, 0);
  // prologue adj prefetch (kk=0 of chunk 0); FIFO = [stage0 x4][pa x4]
  vf4 pa0 = __builtin_nontemporal_load((const vf4*)a0p);
  vf4 pa1 = __builtin_nontemporal_load((const vf4*)a0p + 1);
  vf4 pa2 = __builtin_nontemporal_load((const vf4*)a1p);
  vf4 pa3 = __builtin_nontemporal_load((const vf4*)a1p + 1);

#pragma unroll 1
  for (int ch = 0; ch < CHUNKS; ++ch) {
    const int b = ch & 1;
    // Retire everything except the 4 newest (adj prefetch). stage(ch) is older
    // -> guaranteed landed in lds[b]; then sync waves. No vmcnt(0) drain.
    asm volatile("s_waitcnt vmcnt(4)" ::: "memory");
    __builtin_amdgcn_s_barrier();
    __builtin_amdgcn_sched_barrier(0);
    if (ch + 1 < CHUNKS) stage(ch + 1, b ^ 1);
    __builtin_amdgcn_sched_barrier(0);  // pin stage before subsequent adj loads
#pragma unroll
    for (int kk = 0; kk < 4; ++kk) {
      // prefetch next kk (kk==3 -> kk0 of next chunk at +128 floats)
      const bool more = (kk < 3) || (ch + 1 < CHUNKS);
      const int nc = (kk + 1) * 32;
      vf4 na0, na1, na2, na3;
      if (more) {
        na0 = __builtin_nontemporal_load((const vf4*)(a0p + nc));
        na1 = __builtin_nontemporal_load((const vf4*)(a0p + nc) + 1);
        na2 = __builtin_nontemporal_load((const vf4*)(a1p + nc));
        na3 = __builtin_nontemporal_load((const vf4*)(a1p + nc) + 1);
      }
      vbf8 af0 = frag_trunc(pa0, pa1);
      vbf8 af1 = frag_trunc(pa2, pa3);
#pragma unroll
      for (int f = 0; f < 8; ++f) {
        vbf8 bfr = *(const vbf8*)&lds[b][(size_t)(kk * 512 + f * 64 + lane) * 8];
        acc0[f] = __builtin_amdgcn_mfma_f32_16x16x32_bf16(af0, bfr, acc0[f], 0, 0, 0);
        acc1[f] = __builtin_amdgcn_mfma_f32_16x16x32_bf16(af1, bfr, acc1[f], 0, 0, 0);
      }
      if (more) { pa0 = na0; pa1 = na1; pa2 = na2; pa3 = na3; }
    }
    a0p += 128; a1p += 128;
  }

  // C/D: col n = f*16+r, row m = q*4+reg (+16 for acc1). Cpart[slice][n][m].
#pragma unroll
  for (int f = 0; f < 8; ++f) {
    short4 v0, v1;
    v0.x = (short)bf_rne(acc0[f][0]); v0.y = (short)bf_rne(acc0[f][1]);
    v0.z = (short)bf_rne(acc0[f][2]); v0.w = (short)bf_rne(acc0[f][3]);
    v1.x = (short)bf_rne(acc1[f][0]); v1.y = (short)bf_rne(acc1[f][1]);
    v1.z = (short)bf_rne(acc1[f][2]); v1.w = (short)bf_rne(acc1[f][3]);
    unsigned short* d0 = Cpart + ((size_t)slice * 128 + f * 16 + r) * NN + m0 + q * 4;
    *(short4*)d0 = v0;
    *(short4*)(d0 + 16) = v1;
  }
}

// ---------------- k3a: H[n][m] = PReLU(sum_s Cpart[s][n][m] + b) (bf16, 2 MB),
//                  csum[h] += sum_m H * msk  (for n < 64) ----------------------
__global__ __launch_bounds__(256) void k3a(
    const unsigned short* __restrict__ Cpart, const float* __restrict__ bias,
    const float* __restrict__ alpha_p, const float* __restrict__ msk,
    unsigned short* __restrict__ H, float* __restrict__ csum) {
  const int n = blockIdx.x >> 2, chunk = blockIdx.x & 3;  // 512 blocks
  const int t = threadIdx.x;
  const int m0 = chunk * 2048 + t * 8;
  const float alpha = alpha_p[0], b = bias[n & 63];
  float v[8] = {};
#pragma unroll
  for (int s = 0; s < SPLIT; ++s) {
    vbf8 c = *(const vbf8*)(Cpart + ((size_t)s * 128 + n) * NN + m0);
#pragma unroll
    for (int j = 0; j < 8; ++j) v[j] += bf_to_f((unsigned short)c[j]);
  }
  FragU hout;
  float acc = 0.f;
#pragma unroll
  for (int j = 0; j < 8; ++j) {
    float x = v[j] + b;
    x = x > 0.f ? x : alpha * x;
    hout.s[j] = bf_rne(x);
    acc += x * msk[m0 + j];
  }
  *(vbf8*)(H + (size_t)n * NN + m0) = hout.v;
  if (n < 64) {
    __shared__ float red[256];
    red[t] = acc;
    __syncthreads();
    for (int off = 128; off > 32; off >>= 1) {
      if (t < off) red[t] += red[t + off];
      __syncthreads();
    }
    if (t < 32) {
      float x = red[t] + red[t + 32];
#pragma unroll
      for (int off = 16; off > 0; off >>= 1) x += __shfl_down(x, off, 64);
      if (t == 0) atomicAdd(&csum[n], x);
    }
  }
}

// ---------------- k4: fused (ex-k3b) msksum -> c -> wc, then
//                  sc{1,2}[m] = sum_h H[(half*64+h)][m] * wc[h] + db ----------
// H is 2 MB (L2/L3-resident); 128 blocks, wave w covers n = w*32..w*32+31.
// Each block redundantly computes msksum/c/wc (trivial, L2-hit) — saves one
// kernel dispatch + the csum->wc global round trip.
__global__ __launch_bounds__(256) void k4_sc(
    const unsigned short* __restrict__ H, const float* __restrict__ msk,
    const float* __restrict__ csum, const float* __restrict__ discw,
    const float* __restrict__ discb, float* __restrict__ out) {
  const int t = threadIdx.x, lane = t & 63, w = t >> 6;
  __shared__ float red2[256];
  __shared__ float c_sh[64];
  __shared__ float wc_sh[64];
  // msksum
  float ms = 0.f;
#pragma unroll
  for (int i = 0; i < 32; ++i) ms += msk[t + 256 * i];
  red2[t] = ms;
  __syncthreads();
  for (int off = 128; off > 0; off >>= 1) {
    if (t < off) red2[t] += red2[t + off];
    __syncthreads();
  }
  const float msum = red2[0];
  if (t < 64) c_sh[t] = 1.f / (1.f + __expf(-csum[t] / msum));
  __syncthreads();
  if (t < 64) {
    float wv = 0.f;
#pragma unroll
    for (int k = 0; k < 64; ++k) wv += discw[t * 64 + k] * c_sh[k];
    wc_sh[t] = wv;
  }
  __syncthreads();

  const int m = blockIdx.x * 64 + lane;    // grid 128
  float s = 0.f;
#pragma unroll
  for (int i = 0; i < 32; ++i) {
    const int n = w * 32 + i;
    s += bf_to_f(H[(size_t)n * NN + m]) * wc_sh[n & 63];
  }
  __shared__ float red[4][64];
  red[w][lane] = s;
  __syncthreads();
  if (t < 128) {
    const int half = t >> 6, mm = t & 63;
    out[(size_t)half * NN + blockIdx.x * 64 + mm] =
        red[half * 2][mm] + red[half * 2 + 1][mm] + discb[0];
  }
}

extern "C" void kernel_launch(void* const* d_in, const int* in_sizes, int n_in,
                              void* d_out, int out_size, void* d_ws, size_t ws_size,
                              hipStream_t stream) {
  const float* seq1  = (const float*)d_in[0];
  const float* seq2  = (const float*)d_in[1];
  const float* adj   = (const float*)d_in[2];
  const float* msk   = (const float*)d_in[3];
  const float* fcw   = (const float*)d_in[4];
  const float* bias  = (const float*)d_in[5];
  const float* alpha = (const float*)d_in[6];
  const float* discw = (const float*)d_in[7];
  const float* discb = (const float*)d_in[8];
  float* out = (float*)d_out;
  char* ws = (char*)d_ws;

  unsigned short* Bt    = (unsigned short*)ws;                          // 2 MB
  unsigned short* Cpart = (unsigned short*)(ws + (size_t)(2 << 20));    // 32 MB
  unsigned short* H     = (unsigned short*)(ws + (size_t)(34 << 20));   // 2 MB
  float* csum           = (float*)(ws + (size_t)(36 << 20));            // 64 f

  hipLaunchKernelGGL(k1_fts, dim3(256), dim3(256), 0, stream, seq1, seq2, fcw, Bt, csum);
  hipLaunchKernelGGL(k2_agg, dim3(32 * SPLIT), dim3(512), 0, stream, adj, Bt, Cpart);
  hipLaunchKernelGGL(k3a, dim3(512), dim3(256), 0, stream, Cpart, bias, alpha, msk, H, csum);
  hipLaunchKernelGGL(k4_sc, dim3(128), dim3(256), 0, stream, H, msk, csum, discw, discb, out);
}

// Round 2
// 402.531 us; speedup vs baseline: 1.0600x; 1.0600x over previous
//
#include <hip/hip_runtime.h>
#include <cstdint>
#include <cstddef>

#define NN 8192
#define FIN 256
#define HH 64
#define SPLIT 8
#define KLEN (NN / SPLIT)   // 1024

typedef float vf4 __attribute__((ext_vector_type(4)));
typedef short vbf8 __attribute__((ext_vector_type(8)));

__device__ inline unsigned pk_trunc(float lo, float hi) {
  return __builtin_amdgcn_perm(__float_as_uint(hi), __float_as_uint(lo), 0x07060302u);
}
__device__ inline unsigned short bf_rne(float x) {
  unsigned u = __float_as_uint(x);
  return (unsigned short)((u + 0x7FFFu + ((u >> 16) & 1u)) >> 16);
}
__device__ inline float bf_to_f(unsigned short s) {
  return __uint_as_float(((unsigned)s) << 16);
}

union FragU { unsigned u[4]; unsigned short s[8]; vbf8 v; };

__device__ inline vbf8 frag_trunc(vf4 a, vf4 b) {
  FragU t;
  t.u[0] = pk_trunc(a[0], a[1]);
  t.u[1] = pk_trunc(a[2], a[3]);
  t.u[2] = pk_trunc(b[0], b[1]);
  t.u[3] = pk_trunc(b[2], b[3]);
  return t.v;
}
__device__ inline vbf8 frag_rne(vf4 a, vf4 b) {
  FragU t;
  t.s[0] = bf_rne(a[0]); t.s[1] = bf_rne(a[1]); t.s[2] = bf_rne(a[2]); t.s[3] = bf_rne(a[3]);
  t.s[4] = bf_rne(b[0]); t.s[5] = bf_rne(b[1]); t.s[6] = bf_rne(b[2]); t.s[7] = bf_rne(b[3]);
  return t.v;
}

__device__ inline void gl_lds16(const void* g, void* l) {
  __builtin_amdgcn_global_load_lds(
      (const __attribute__((address_space(1))) void*)g,
      (__attribute__((address_space(3))) void*)l, 16, 0, 0);
}

// ---------------- k1: fts = seq @ fc_w^T (both seqs), write Bt[n][k] bf16 -----
__global__ __launch_bounds__(256) void k1_fts(
    const float* __restrict__ seq1, const float* __restrict__ seq2,
    const float* __restrict__ fcw, unsigned short* __restrict__ Bt,
    float* __restrict__ csum) {
  const int bx = blockIdx.x;           // 256 blocks
  const int s = bx & 1, mb = bx >> 1;
  const int wave = threadIdx.x >> 6, lane = threadIdx.x & 63;
  const int r = lane & 15, q = lane >> 4;
  const int m0 = mb * 64 + wave * 16;
  if (bx == 0 && threadIdx.x < 64) csum[threadIdx.x] = 0.f;
  const float* seq = s ? seq2 : seq1;
  const float* ap = seq + (size_t)(m0 + r) * FIN + q * 8;
  const float* bp = fcw + (size_t)r * FIN + q * 8;
  vf4 acc[4] = {};
#pragma unroll
  for (int kk = 0; kk < FIN; kk += 32) {
    vf4 a0 = *(const vf4*)ap;
    vf4 a1 = *(const vf4*)(ap + 4);
    vbf8 af = frag_rne(a0, a1);
#pragma unroll
    for (int f = 0; f < 4; ++f) {
      vf4 b0 = *(const vf4*)(bp + (size_t)f * 16 * FIN);
      vf4 b1 = *(const vf4*)(bp + (size_t)f * 16 * FIN + 4);
      vbf8 bfr = frag_rne(b0, b1);
      acc[f] = __builtin_amdgcn_mfma_f32_16x16x32_bf16(af, bfr, acc[f], 0, 0, 0);
    }
    ap += 32; bp += 32;
  }
#pragma unroll
  for (int f = 0; f < 4; ++f) {
    short4 v;
    v.x = (short)bf_rne(acc[f][0]);
    v.y = (short)bf_rne(acc[f][1]);
    v.z = (short)bf_rne(acc[f][2]);
    v.w = (short)bf_rne(acc[f][3]);
    unsigned short* dst = Bt + (size_t)(64 * s + 16 * f + r) * NN + m0 + q * 4;
    *(short4*)dst = v;
  }
}

// ---------------- k2: Cpart[slice][n][m] = (adj[:,ks] @ B[ks,:])^T -----------
// SPLIT=8 re-tile: grid = 64 m-blocks (128 rows) x 8 slices = 512 blocks.
// Block: 512 thr = 8 waves; wave w owns 16 m-rows x 128 n -> acc[8] (32 VGPR).
// Every adj element still read exactly once; Cpart halves to 16 MB (saves a
// 32 MB HBM round-trip vs SPLIT=16). Plain __syncthreads double-buffer loop
// (the 412 us structure): per-chunk stage had a full chunk of compute+stream
// between issue and drain, so counted-vmcnt bought nothing (R1 post-mortem).
__global__ __launch_bounds__(512, 4) void k2_agg(
    const float* __restrict__ adj, const unsigned short* __restrict__ Bt,
    unsigned short* __restrict__ Cpart) {
  constexpr int CHUNKS = KLEN / 128;       // 8
  __shared__ unsigned short lds[2][16384]; // 2 x 32 KB
  const int bx = blockIdx.x;
  const int slice = bx & (SPLIT - 1), mb = bx / SPLIT;
  const int wave = threadIdx.x >> 6, lane = threadIdx.x & 63;
  const int r = lane & 15, q = lane >> 4;
  const int m0 = mb * 128 + wave * 16;
  const int k0 = slice * KLEN;

  // granule g (16 B) at lds offset g*16 holds Bt[f*16+r'][k0+ch*128+kk*32+q'*8]
  // with g = kk*512 + f*64 + q'*16 + r'; compute-side ds_read for frag (kk,f)
  // at granules (kk*512+f*64) + lane is then lane-contiguous, conflict-free.
  auto stage = [&](int ch, int b) {
#pragma unroll
    for (int j = 0; j < 4; ++j) {
      const int g = j * 512 + wave * 64 + lane;
      const int r_ = g & 15, q_ = (g >> 4) & 3, f_ = (g >> 6) & 7, kk_ = g >> 9;
      const unsigned short* src =
          Bt + (size_t)(f_ * 16 + r_) * NN + k0 + ch * 128 + kk_ * 32 + q_ * 8;
      gl_lds16(src, &lds[b][(size_t)(j * 512 + wave * 64) * 8]);
    }
  };

  vf4 acc[8] = {};
  const float* ap = adj + (size_t)(m0 + r) * NN + k0 + q * 8;

  stage(0, 0);
#pragma unroll 1
  for (int ch = 0; ch < CHUNKS; ++ch) {
    __syncthreads();                       // staging of lds[ch&1] complete
    if (ch + 1 < CHUNKS) stage(ch + 1, (ch + 1) & 1);
    const int b = ch & 1;
#pragma unroll
    for (int kk = 0; kk < 4; ++kk) {
      const int kc = ch * 128 + kk * 32;
      vf4 a0 = __builtin_nontemporal_load((const vf4*)(ap + kc));
      vf4 a1 = __builtin_nontemporal_load((const vf4*)(ap + kc) + 1);
      vbf8 af = frag_trunc(a0, a1);
#pragma unroll
      for (int f = 0; f < 8; ++f) {
        vbf8 bfr = *(const vbf8*)&lds[b][(size_t)(kk * 512 + f * 64 + lane) * 8];
        acc[f] = __builtin_amdgcn_mfma_f32_16x16x32_bf16(af, bfr, acc[f], 0, 0, 0);
      }
    }
  }

  // C/D: col n = f*16+r, row m = q*4+reg. Cpart[slice][n][m].
#pragma unroll
  for (int f = 0; f < 8; ++f) {
    short4 v;
    v.x = (short)bf_rne(acc[f][0]); v.y = (short)bf_rne(acc[f][1]);
    v.z = (short)bf_rne(acc[f][2]); v.w = (short)bf_rne(acc[f][3]);
    unsigned short* d0 = Cpart + ((size_t)slice * 128 + f * 16 + r) * NN + m0 + q * 4;
    *(short4*)d0 = v;
  }
}

// ---------------- k3a: H[n][m] = PReLU(sum_s Cpart[s][n][m] + b) (bf16, 2 MB),
//                  csum[h] += sum_m H * msk  (for n < 64) ----------------------
__global__ __launch_bounds__(256) void k3a(
    const unsigned short* __restrict__ Cpart, const float* __restrict__ bias,
    const float* __restrict__ alpha_p, const float* __restrict__ msk,
    unsigned short* __restrict__ H, float* __restrict__ csum) {
  const int n = blockIdx.x >> 2, chunk = blockIdx.x & 3;  // 512 blocks
  const int t = threadIdx.x;
  const int m0 = chunk * 2048 + t * 8;
  const float alpha = alpha_p[0], b = bias[n & 63];
  float v[8] = {};
#pragma unroll
  for (int s = 0; s < SPLIT; ++s) {
    vbf8 c = *(const vbf8*)(Cpart + ((size_t)s * 128 + n) * NN + m0);
#pragma unroll
    for (int j = 0; j < 8; ++j) v[j] += bf_to_f((unsigned short)c[j]);
  }
  FragU hout;
  float acc = 0.f;
#pragma unroll
  for (int j = 0; j < 8; ++j) {
    float x = v[j] + b;
    x = x > 0.f ? x : alpha * x;
    hout.s[j] = bf_rne(x);
    acc += x * msk[m0 + j];
  }
  *(vbf8*)(H + (size_t)n * NN + m0) = hout.v;
  if (n < 64) {
    __shared__ float red[256];
    red[t] = acc;
    __syncthreads();
    for (int off = 128; off > 32; off >>= 1) {
      if (t < off) red[t] += red[t + off];
      __syncthreads();
    }
    if (t < 32) {
      float x = red[t] + red[t + 32];
#pragma unroll
      for (int off = 16; off > 0; off >>= 1) x += __shfl_down(x, off, 64);
      if (t == 0) atomicAdd(&csum[n], x);
    }
  }
}

// ---------------- k4: fused (ex-k3b) msksum -> c -> wc, then
//                  sc{1,2}[m] = sum_h H[(half*64+h)][m] * wc[h] + db ----------
// H is 2 MB (L2/L3-resident); 128 blocks, wave w covers n = w*32..w*32+31.
// Each block redundantly computes msksum/c/wc (trivial, L2-hit) — saves one
// kernel dispatch + the csum->wc global round trip.
__global__ __launch_bounds__(256) void k4_sc(
    const unsigned short* __restrict__ H, const float* __restrict__ msk,
    const float* __restrict__ csum, const float* __restrict__ discw,
    const float* __restrict__ discb, float* __restrict__ out) {
  const int t = threadIdx.x, lane = t & 63, w = t >> 6;
  __shared__ float red2[256];
  __shared__ float c_sh[64];
  __shared__ float wc_sh[64];
  // msksum
  float ms = 0.f;
#pragma unroll
  for (int i = 0; i < 32; ++i) ms += msk[t + 256 * i];
  red2[t] = ms;
  __syncthreads();
  for (int off = 128; off > 0; off >>= 1) {
    if (t < off) red2[t] += red2[t + off];
    __syncthreads();
  }
  const float msum = red2[0];
  if (t < 64) c_sh[t] = 1.f / (1.f + __expf(-csum[t] / msum));
  __syncthreads();
  if (t < 64) {
    float wv = 0.f;
#pragma unroll
    for (int k = 0; k < 64; ++k) wv += discw[t * 64 + k] * c_sh[k];
    wc_sh[t] = wv;
  }
  __syncthreads();

  const int m = blockIdx.x * 64 + lane;    // grid 128
  float s = 0.f;
#pragma unroll
  for (int i = 0; i < 32; ++i) {
    const int n = w * 32 + i;
    s += bf_to_f(H[(size_t)n * NN + m]) * wc_sh[n & 63];
  }
  __shared__ float red[4][64];
  red[w][lane] = s;
  __syncthreads();
  if (t < 128) {
    const int half = t >> 6, mm = t & 63;
    out[(size_t)half * NN + blockIdx.x * 64 + mm] =
        red[half * 2][mm] + red[half * 2 + 1][mm] + discb[0];
  }
}

extern "C" void kernel_launch(void* const* d_in, const int* in_sizes, int n_in,
                              void* d_out, int out_size, void* d_ws, size_t ws_size,
                              hipStream_t stream) {
  const float* seq1  = (const float*)d_in[0];
  const float* seq2  = (const float*)d_in[1];
  const float* adj   = (const float*)d_in[2];
  const float* msk   = (const float*)d_in[3];
  const float* fcw   = (const float*)d_in[4];
  const float* bias  = (const float*)d_in[5];
  const float* alpha = (const float*)d_in[6];
  const float* discw = (const float*)d_in[7];
  const float* discb = (const float*)d_in[8];
  float* out = (float*)d_out;
  char* ws = (char*)d_ws;

  unsigned short* Bt    = (unsigned short*)ws;                          // 2 MB
  unsigned short* Cpart = (unsigned short*)(ws + (size_t)(2 << 20));    // 16 MB
  unsigned short* H     = (unsigned short*)(ws + (size_t)(18 << 20));   // 2 MB
  float* csum           = (float*)(ws + (size_t)(20 << 20));            // 64 f

  hipLaunchKernelGGL(k1_fts, dim3(256), dim3(256), 0, stream, seq1, seq2, fcw, Bt, csum);
  hipLaunchKernelGGL(k2_agg, dim3(64 * SPLIT), dim3(512), 0, stream, adj, Bt, Cpart);
  hipLaunchKernelGGL(k3a, dim3(512), dim3(256), 0, stream, Cpart, bias, alpha, msk, H, csum);
  hipLaunchKernelGGL(k4_sc, dim3(128), dim3(256), 0, stream, H, msk, csum, discw, discb, out);
}